// Round 1
// baseline (98.947 us; speedup 1.0000x reference)
//
#include <hip/hip_runtime.h>

// Problem: B=4, S=4096, DIM=2048, BITS=32, HEXPERTS=4  (all f32)
// out[t,d] = x[t,d] * ( sum_e v[t,e]*aggr_w[e]*emb[idx[t,e],d] + aggr_b )
// where (v,idx) = top4(softmax(x[t,:]@A1_w.T + A1_b)) sorted descending,
// ties -> lower index (lax.top_k semantics).

#define NTOK 16384
#define DIMV 2048

// ---------------------------------------------------------------------------
// K1: router. 512 blocks x 256 threads. Block = 32 tokens.
// Wave w owns dims [512w, 512w+512) (partial logits), reduced via LDS at end.
// Lane: tg=lane&7 -> tokens {4tg..4tg+3}; kg=lane>>3 -> bits {4kg..4kg+3}.
// 16-dim chunks staged global->reg->LDS (per-wave private buffers, no barriers
// in main loop; same-wave DS ordering makes write->read safe).
// LDS rows padded to 18 floats: ds_read_b64 lanes land 2-way/bank (free).
// ---------------------------------------------------------------------------
__global__ __launch_bounds__(256, 2) void router_k(
    const float* __restrict__ x,
    const float* __restrict__ A1w,
    const float* __restrict__ A1b,
    const float* __restrict__ aggw,
    float* __restrict__ gates)
{
    __shared__ float smem[4608];          // 4 waves * (576 x + 576 w) floats
    const int tid  = threadIdx.x;
    const int wid  = tid >> 6;
    const int lane = tid & 63;
    const int tg   = lane & 7;
    const int kg   = lane >> 3;
    const int tok0 = blockIdx.x << 5;     // 32 tokens per block
    const int d0   = wid << 9;            // wave's dim base

    float* xs  = smem + wid * 1152;       // [32 rows][18]
    float* wsx = xs + 576;                // [32 rows][18]

    // staging map: 64 lanes cover 16 rows x 64B; two insts -> 32 rows
    const int srow = lane >> 2;           // 0..15
    const int scol = (lane & 3) << 2;     // 0,4,8,12

    const float* xg0 = x   + (size_t)(tok0 + srow)      * DIMV + d0 + scol;
    const float* xg1 = x   + (size_t)(tok0 + srow + 16) * DIMV + d0 + scol;
    const float* wg0 = A1w + (size_t)(srow)             * DIMV + d0 + scol;
    const float* wg1 = A1w + (size_t)(srow + 16)        * DIMV + d0 + scol;

    float2 acc[4][4];
    #pragma unroll
    for (int i = 0; i < 4; ++i)
        #pragma unroll
        for (int j = 0; j < 4; ++j) acc[i][j] = make_float2(0.f, 0.f);

    // prefetch chunk 0
    float4 px0 = *(const float4*)(xg0);
    float4 px1 = *(const float4*)(xg1);
    float4 pw0 = *(const float4*)(wg0);
    float4 pw1 = *(const float4*)(wg1);

    for (int c = 0; c < 32; ++c) {
        // stage current chunk into LDS (float2 pieces: pad-18 rows are 8B-aligned)
        {
            float* a = xs  + srow * 18 + scol;
            float* b = xs  + (srow + 16) * 18 + scol;
            float* d = wsx + srow * 18 + scol;
            float* e = wsx + (srow + 16) * 18 + scol;
            *(float2*)(a)     = make_float2(px0.x, px0.y);
            *(float2*)(a + 2) = make_float2(px0.z, px0.w);
            *(float2*)(b)     = make_float2(px1.x, px1.y);
            *(float2*)(b + 2) = make_float2(px1.z, px1.w);
            *(float2*)(d)     = make_float2(pw0.x, pw0.y);
            *(float2*)(d + 2) = make_float2(pw0.z, pw0.w);
            *(float2*)(e)     = make_float2(pw1.x, pw1.y);
            *(float2*)(e + 2) = make_float2(pw1.z, pw1.w);
        }
        // prefetch next chunk (wraps to 0 at the end; harmless)
        {
            const int cn = (c + 1) & 31;
            px0 = *(const float4*)(xg0 + cn * 16);
            px1 = *(const float4*)(xg1 + cn * 16);
            pw0 = *(const float4*)(wg0 + cn * 16);
            pw1 = *(const float4*)(wg1 + cn * 16);
        }
        // compute current chunk: 8 d-pair steps, 4x4 register tile
        #pragma unroll
        for (int dd = 0; dd < 16; dd += 2) {
            float2 xv[4], wv[4];
            #pragma unroll
            for (int i = 0; i < 4; ++i)
                xv[i] = *(const float2*)&xs[(4 * tg + i) * 18 + dd];
            #pragma unroll
            for (int j = 0; j < 4; ++j)
                wv[j] = *(const float2*)&wsx[(4 * kg + j) * 18 + dd];
            #pragma unroll
            for (int i = 0; i < 4; ++i)
                #pragma unroll
                for (int j = 0; j < 4; ++j) {
                    acc[i][j].x = fmaf(xv[i].x, wv[j].x, acc[i][j].x);
                    acc[i][j].y = fmaf(xv[i].y, wv[j].y, acc[i][j].y);
                }
        }
    }

    // cross-wave reduction: red[32 tokens][132] (128 data + 4 pad, 16B-aligned rows)
    __syncthreads();
    float* red = smem;
    #pragma unroll
    for (int i = 0; i < 4; ++i)
        #pragma unroll
        for (int j = 0; j < 4; ++j)
            red[(4 * tg + i) * 132 + (4 * kg + j) * 4 + wid] =
                acc[i][j].x + acc[i][j].y;
    __syncthreads();

    // softmax + top4 + gate precompute: one thread per token (32 of 256)
    if (tid < 32) {
        const int t = tid;
        float l[32];
        #pragma unroll
        for (int k = 0; k < 32; ++k) {
            float4 p = *(const float4*)&red[t * 132 + k * 4];
            l[k] = (p.x + p.y) + (p.z + p.w) + A1b[k];
        }
        float m = l[0];
        #pragma unroll
        for (int k = 1; k < 32; ++k) m = fmaxf(m, l[k]);
        float s = 0.f;
        #pragma unroll
        for (int k = 0; k < 32; ++k) { l[k] = expf(l[k] - m); s += l[k]; }
        const float inv = 1.0f / s;

        unsigned used = 0u;
        float gv[4]; unsigned iv[4];
        #pragma unroll
        for (int e = 0; e < 4; ++e) {
            float best = -1.f; int bi = 0;
            #pragma unroll
            for (int k = 0; k < 32; ++k) {
                bool ok = !((used >> k) & 1u) && (l[k] > best);
                best = ok ? l[k] : best;
                bi   = ok ? k    : bi;
            }
            used |= (1u << bi);
            gv[e] = best * inv * aggw[e];   // pre-multiply gate by aggr_w[e]
            iv[e] = (unsigned)bi;
        }
        float* gp = gates + (size_t)(tok0 + t) * 8;
        *(float4*)gp = make_float4(gv[0], gv[1], gv[2], gv[3]);
        *(float4*)(gp + 4) = make_float4(__uint_as_float(iv[0]), __uint_as_float(iv[1]),
                                         __uint_as_float(iv[2]), __uint_as_float(iv[3]));
    }
}

// ---------------------------------------------------------------------------
// K2: gather + combine + residual multiply. One block per token, streaming.
// emb (256 KB) is L2-resident; x re-read should largely hit L3 after K1.
// ---------------------------------------------------------------------------
__global__ __launch_bounds__(256) void moe_out_k(
    const float* __restrict__ x,
    const float* __restrict__ emb,
    const float* __restrict__ gates,
    const float* __restrict__ aggb,
    float* __restrict__ out)
{
    const int t   = blockIdx.x;
    const int tid = threadIdx.x;
    const float* gp = gates + (size_t)t * 8;
    const float4 g  = *(const float4*)gp;
    const float4 ibits = *(const float4*)(gp + 4);
    const unsigned i0 = __float_as_uint(ibits.x);
    const unsigned i1 = __float_as_uint(ibits.y);
    const unsigned i2 = __float_as_uint(ibits.z);
    const unsigned i3 = __float_as_uint(ibits.w);
    const float b = aggb[0];
    const size_t base = (size_t)t * DIMV;

    #pragma unroll
    for (int h = 0; h < DIMV; h += 1024) {
        const int d = h + (tid << 2);
        const float4 xv = *(const float4*)&x[base + d];
        const float4 e0 = *(const float4*)&emb[(size_t)i0 * DIMV + d];
        const float4 e1 = *(const float4*)&emb[(size_t)i1 * DIMV + d];
        const float4 e2 = *(const float4*)&emb[(size_t)i2 * DIMV + d];
        const float4 e3 = *(const float4*)&emb[(size_t)i3 * DIMV + d];
        float4 a, o;
        a.x = fmaf(g.x, e0.x, fmaf(g.y, e1.x, fmaf(g.z, e2.x, fmaf(g.w, e3.x, b))));
        a.y = fmaf(g.x, e0.y, fmaf(g.y, e1.y, fmaf(g.z, e2.y, fmaf(g.w, e3.y, b))));
        a.z = fmaf(g.x, e0.z, fmaf(g.y, e1.z, fmaf(g.z, e2.z, fmaf(g.w, e3.z, b))));
        a.w = fmaf(g.x, e0.w, fmaf(g.y, e1.w, fmaf(g.z, e2.w, fmaf(g.w, e3.w, b))));
        o.x = xv.x * a.x; o.y = xv.y * a.y; o.z = xv.z * a.z; o.w = xv.w * a.w;
        *(float4*)&out[base + d] = o;
    }
}

extern "C" void kernel_launch(void* const* d_in, const int* in_sizes, int n_in,
                              void* d_out, int out_size, void* d_ws, size_t ws_size,
                              hipStream_t stream)
{
    (void)in_sizes; (void)n_in; (void)out_size; (void)ws_size;
    const float* x    = (const float*)d_in[0];
    const float* A1w  = (const float*)d_in[1];
    const float* A1b  = (const float*)d_in[2];
    const float* emb  = (const float*)d_in[3];
    const float* aggw = (const float*)d_in[4];
    const float* aggb = (const float*)d_in[5];
    float* out   = (float*)d_out;
    float* gates = (float*)d_ws;          // 16384 tokens * 8 f32 = 512 KB

    router_k<<<512, 256, 0, stream>>>(x, A1w, A1b, aggw, gates);
    moe_out_k<<<NTOK, 256, 0, stream>>>(x, emb, gates, aggb, out);
}